// Round 6
// baseline (793.506 us; speedup 1.0000x reference)
//
#include <hip/hip_runtime.h>
#include <hip/hip_cooperative_groups.h>
#include <stdint.h>

namespace cg = cooperative_groups;

#define HW 16384
#define NI 64
#define NM 256
#define WORDS 256          // 16384 / 64 bits
#define GRID 512           // 2 blocks/CU co-residency — easily achievable at <=256 VGPR
#define TPB 256
#define NTHREADS (GRID * TPB)  // 131072

// ws layout (~40 MB used)
#define OFF_STATE_A 0u
#define OFF_STATE_B (1u << 20)
#define OFF_PACKED  (2u << 20)
#define OFF_DIOU    0x280000u
#define OFF_COMPM   0x2C0000u
#define OFF_CNT     0x2C1000u
#define OFF_CRFK    0x300000u

// ===================== shared phase bodies (identical numerics both paths) ==

// setup: state init + crfk weights + pack + counter zero. gid in [0, NTHREADS).
__device__ __forceinline__ void dev_setup(int gid,
    const float* __restrict__ seg, const float* __restrict__ feat,
    const float* __restrict__ x, const float* __restrict__ targets,
    unsigned char* __restrict__ state, float* __restrict__ crfk,
    unsigned long long* __restrict__ packed, int* __restrict__ counters) {
    #pragma clang fp contract(off)
    for (int u = gid; u < 262144; u += NTHREADS) {
        const int px0 = u * 4;
        const int b = px0 >> 14;
        const int p0 = px0 & (HW - 1);
        const int y = p0 >> 7, x0 = p0 & 127;

        // state byte: bit0 = s1 (ret1==0.55f), bit1 = s0, bit2 = target
        const float4 xv = *(const float4*)(x + px0);
        const float4 tv = *(const float4*)(targets + px0);
        float xs[4] = {xv.x, xv.y, xv.z, xv.w};
        float ts[4] = {tv.x, tv.y, tv.z, tv.w};
        uint32_t st = 0;
        for (int j = 0; j < 4; ++j) {
            float xt = xs[j] * ts[j];
            int b1 = (xt > 0.5f) ? 1 : 0;
            int tb = (ts[j] > 0.5f) ? 1 : 0;
            st |= (uint32_t)(b1 | ((b1 ^ 1) << 1) | (tb << 2)) << (8 * j);
        }
        *(uint32_t*)(state + px0) = st;

        // crfk[b][k][p]: exact reference op order (c+10, zero-pad OOB, seq ch sums)
        const float* f = feat + (size_t)b * 3 * HW;
        float c0[4], c1[4], c2[4];
        for (int j = 0; j < 4; ++j) {
            c0[j] = f[p0 + j] + 10.0f;
            c1[j] = f[HW + p0 + j] + 10.0f;
            c2[j] = f[2 * HW + p0 + j] + 10.0f;
        }
        for (int k = 0; k < 9; ++k) {
            int dy = k / 3 - 1, dx = k % 3 - 1;
            int yy = y + dy;
            float kw[4];
            for (int j = 0; j < 4; ++j) {
                int xx = x0 + j + dx;
                float u0 = 0.0f, u1 = 0.0f, u2 = 0.0f;
                if ((unsigned)yy < 128u && (unsigned)xx < 128u) {
                    int q = yy * 128 + xx;
                    u0 = f[q] + 10.0f;
                    u1 = f[HW + q] + 10.0f;
                    u2 = f[2 * HW + q] + 10.0f;
                }
                float d0 = u0 - c0[j], d1 = u1 - c1[j], d2 = u2 - c2[j];
                float ss = d0 * d0;
                ss = ss + d1 * d1;
                ss = ss + d2 * d2;
                float color = (-ss) / 0.5f;                       // -sum / (2*theta0^2)
                float sp = (float)(dy * dy + dx * dx) / 1800.0f;  // spatial / (2*theta1^2)
                kw[j] = 3.0f * expf(color - sp);
            }
            *(float4*)&crfk[(((size_t)b * 9 + k) << 14) + p0] =
                make_float4(kw[0], kw[1], kw[2], kw[3]);
        }
    }

    // pack: 2048 waves x 32 (mask, word) pairs
    const int wv = gid >> 6, lane = gid & 63;
    for (int t = 0; t < 32; ++t) {
        int gwi = wv * 32 + t;       // [0, 65536)
        int i = gwi >> 8, w = gwi & 255;
        float v = seg[(size_t)i * HW + w * 64 + lane];
        unsigned long long m = __ballot(v > 0.5f);
        if (lane == 0) packed[w * NM + i] = m;
    }

    if (gid < NI) counters[gid] = 0;
}

__device__ __forceinline__ void dev_diou(int bid, int tid, unsigned long long* sh,
    const unsigned long long* __restrict__ packed, const int* __restrict__ labels,
    float* __restrict__ diou) {
    sh[tid] = packed[tid * NM + bid];
    __syncthreads();
    int inter = 0, si = 0, sj = 0;
    for (int w = 0; w < WORDS; ++w) {
        unsigned long long a = sh[w];
        unsigned long long b = packed[w * NM + tid];
        inter += __popcll(a & b);
        si += __popcll(a);
        sj += __popcll(b);
    }
    float d = 0.0f;
    if (tid > bid && labels[bid] == labels[tid]) {
        float u = (float)(si + sj - inter);   // exact integers in f32
        d = (float)inter / u;
    }
    diou[bid * NM + tid] = d;
}

__device__ __forceinline__ void dev_compm(int bid, int tid, float* red,
    const float* __restrict__ diou, float* __restrict__ compm) {
    #pragma clang fp contract(off)
    red[tid] = diou[tid * NM + bid];
    __syncthreads();
    for (int off = 128; off > 0; off >>= 1) {
        if (tid < off) red[tid] = fmaxf(red[tid], red[tid + off]);
        __syncthreads();
    }
    if (tid == 0) {
        float m = red[0];
        float t = m * m;
        compm[bid] = expf(-2.0f * t);
    }
}

__device__ __forceinline__ void dev_coef(int bid, int tid, float* red,
    const float* __restrict__ diou, const float* __restrict__ compm,
    const float* __restrict__ scores_in, float* __restrict__ out) {
    #pragma clang fp contract(off)
    float d = diou[tid * NM + bid];
    float dd = d * d;
    float dec = expf(-2.0f * dd);
    red[tid] = dec / compm[tid];
    __syncthreads();
    for (int off = 128; off > 0; off >>= 1) {
        if (tid < off) red[tid] = fminf(red[tid], red[tid + off]);
        __syncthreads();
    }
    if (tid == 0) out[bid] = scores_in[bid] * red[0];
}

// Two CRF iterations: tiles = 64 images x 8 tiles of 16 rows (512 blocks).
// iterA computes the <=18-row window into LDS (reads complete iter-t state from
// global — identical values to a full sweep); iterB computes 16 rows from LDS.
__device__ __forceinline__ void dev_crf_pair(int bid, int tid, uint32_t* mid32,
    const unsigned char* __restrict__ sIn, unsigned char* __restrict__ sOut,
    const float* __restrict__ crfk) {
    #pragma clang fp contract(off)
    unsigned char* mid = (unsigned char*)mid32;
    const int b = bid >> 3, tile = bid & 7;
    const int r0 = tile * 16;
    const int w0 = r0 - 1;                                // may be -1
    const int wlo = (w0 < 0) ? 0 : w0;
    const int whi = (r0 + 17 > 128) ? 128 : (r0 + 17);
    const unsigned char* sb = sIn + (size_t)b * HW;
    const float* kb = crfk + ((size_t)b * 9 << 14);
    const float l45 = 0.7985076962177716f;  // -log(0.45f)
    const float l55 = 0.5978370007556204f;  // -log(0.55f)

    // ---- iteration A: window rows from global state ----
    for (int p = wlo * 128 + tid * 4; p < whi * 128; p += TPB * 4) {
        int yy0 = p >> 7, xc = p & 127;
        float a0[4] = {0.f, 0.f, 0.f, 0.f}, a1[4] = {0.f, 0.f, 0.f, 0.f};
        for (int k = 0; k < 9; ++k) {
            int dy = k / 3 - 1, dx = k % 3 - 1;
            int yr = yy0 + dy;
            float4 kw4 = *(const float4*)&kb[(k << 14) + p];
            float kw[4] = {kw4.x, kw4.y, kw4.z, kw4.w};
            if ((unsigned)yr < 128u) {
                int qrow = yr * 128;
                for (int j = 0; j < 4; ++j) {
                    int xx = xc + j + dx;
                    if ((unsigned)xx < 128u) {
                        unsigned char sq = sb[qrow + xx];
                        float lx1 = (sq & 1) ? l55 : l45;
                        float lx0 = (sq & 2) ? l55 : l45;
                        float t1 = lx1 * kw[j];  // mul then add (numpy order)
                        float t0 = lx0 * kw[j];
                        a1[j] = a1[j] + t1;
                        a0[j] = a0[j] + t0;
                    }
                }
            }
        }
        uint32_t scw = *(const uint32_t*)(sb + p);
        uint32_t outw = 0;
        for (int j = 0; j < 4; ++j) {
            unsigned char sc = (scw >> (8 * j)) & 0xffu;
            float tval = (sc & 4) ? 1.0f : 0.0f;
            float e1 = expf(-a1[j]);
            float e0 = expf(-a0[j]);
            float m1 = e1 * tval;
            float f1 = m1 + 1e-6f;
            float f0 = e0 + 1e-6f;
            float den = f0 + f1;
            float r1 = f1 / den;
            float r0v = f0 / den;
            int s1 = (r1 > 0.5f) ? 1 : 0;
            int s0 = (r0v > 0.5f) ? 1 : 0;
            outw |= (uint32_t)(s1 | (s0 << 1) | (sc & 4)) << (8 * j);
        }
        *(uint32_t*)&mid[p - w0 * 128] = outw;
    }
    __syncthreads();

    // ---- iteration B: 16 output rows from LDS ----
    const unsigned char* mb = mid - w0 * 128;  // mb[q] == iter t+1 state at pixel q
    for (int p = r0 * 128 + tid * 4; p < (r0 + 16) * 128; p += TPB * 4) {
        int yy0 = p >> 7, xc = p & 127;
        float a0[4] = {0.f, 0.f, 0.f, 0.f}, a1[4] = {0.f, 0.f, 0.f, 0.f};
        for (int k = 0; k < 9; ++k) {
            int dy = k / 3 - 1, dx = k % 3 - 1;
            int yr = yy0 + dy;
            float4 kw4 = *(const float4*)&kb[(k << 14) + p];
            float kw[4] = {kw4.x, kw4.y, kw4.z, kw4.w};
            if ((unsigned)yr < 128u) {   // taps stay within window by construction
                int qrow = yr * 128;
                for (int j = 0; j < 4; ++j) {
                    int xx = xc + j + dx;
                    if ((unsigned)xx < 128u) {
                        unsigned char sq = mb[qrow + xx];
                        float lx1 = (sq & 1) ? l55 : l45;
                        float lx0 = (sq & 2) ? l55 : l45;
                        float t1 = lx1 * kw[j];
                        float t0 = lx0 * kw[j];
                        a1[j] = a1[j] + t1;
                        a0[j] = a0[j] + t0;
                    }
                }
            }
        }
        uint32_t scw = *(const uint32_t*)(mb + p);   // target bit is time-invariant
        uint32_t outw = 0;
        for (int j = 0; j < 4; ++j) {
            unsigned char sc = (scw >> (8 * j)) & 0xffu;
            float tval = (sc & 4) ? 1.0f : 0.0f;
            float e1 = expf(-a1[j]);
            float e0 = expf(-a0[j]);
            float m1 = e1 * tval;
            float f1 = m1 + 1e-6f;
            float f0 = e0 + 1e-6f;
            float den = f0 + f1;
            float r1 = f1 / den;
            float r0v = f0 / den;
            int s1 = (r1 > 0.5f) ? 1 : 0;
            int s0 = (r0v > 0.5f) ? 1 : 0;
            outw |= (uint32_t)(s1 | (s0 << 1) | (sc & 4)) << (8 * j);
        }
        *(uint32_t*)(sOut + (size_t)b * HW + p) = outw;
    }
}

// masks + per-image counts. 512 blocks x 2048 px; 8 blocks per image.
__device__ __forceinline__ void dev_tail(int bid, int tid, int* red,
    const unsigned char* __restrict__ s, float* __restrict__ outMasks,
    int* __restrict__ counters) {
    int cnt = 0;
    for (int st = 0; st < 2; ++st) {
        int p = bid * 2048 + st * 1024 + tid * 4;
        uint32_t w = *(const uint32_t*)(s + p);
        float mv[4];
        for (int j = 0; j < 4; ++j) {
            int v = (w >> (8 * j)) & 1;
            cnt += v;
            mv[j] = (float)v;
        }
        *(float4*)(outMasks + p) = make_float4(mv[0], mv[1], mv[2], mv[3]);
    }
    red[tid] = cnt;
    __syncthreads();
    for (int off = 128; off > 0; off >>= 1) {
        if (tid < off) red[tid] += red[tid + off];
        __syncthreads();
    }
    if (tid == 0) atomicAdd(&counters[bid >> 3], red[0]);
}

__device__ __forceinline__ void dev_valid(int tid, const int* __restrict__ counters,
                                          float* __restrict__ outValid) {
    if (tid < NI) {
        int c = counters[tid];
        // 16384*0.05 = 819.2, 16384*0.95 = 15564.8; counts are integers
        outValid[tid] = (c >= 820 && c <= 15564) ? 1.0f : 0.0f;
    }
}

// ===================== cooperative mega-kernel ==============================
__global__ __launch_bounds__(TPB, 2) void mega_kernel(
    const float* __restrict__ seg, const float* __restrict__ scores,
    const float* __restrict__ feat, const float* __restrict__ x,
    const float* __restrict__ targets, const int* __restrict__ labels,
    float* __restrict__ out, char* __restrict__ ws) {
    cg::grid_group grid = cg::this_grid();
    __shared__ unsigned long long shu64[WORDS];  // 2048 B (also float/int reduce)
    __shared__ uint32_t mid32[19 * 32];          // 2432 B (w0=-1 leaves row 0 unused)

    unsigned char* stateA = (unsigned char*)(ws + OFF_STATE_A);
    unsigned char* stateB = (unsigned char*)(ws + OFF_STATE_B);
    unsigned long long* packed = (unsigned long long*)(ws + OFF_PACKED);
    float* diou = (float*)(ws + OFF_DIOU);
    float* compm = (float*)(ws + OFF_COMPM);
    int* counters = (int*)(ws + OFF_CNT);
    float* crfk = (float*)(ws + OFF_CRFK);

    const int bid = blockIdx.x, tid = threadIdx.x;
    const int gid = bid * TPB + tid;

    dev_setup(gid, seg, feat, x, targets, stateA, crfk, packed, counters);
    grid.sync();
    if (bid < NM) dev_diou(bid, tid, shu64, packed, labels, diou);
    grid.sync();
    if (bid < NM) dev_compm(bid, tid, (float*)shu64, diou, compm);
    grid.sync();
    if (bid < NM) dev_coef(bid, tid, (float*)shu64, diou, compm, scores, out);
    // no sync: CRF pair 1 touches disjoint data (stateA/crfk, synced at setup)

    unsigned char* sA = stateA;
    unsigned char* sB = stateB;
    for (int pr = 0; pr < 5; ++pr) {
        dev_crf_pair(bid, tid, mid32, sA, sB, crfk);
        grid.sync();
        unsigned char* tmp = sA; sA = sB; sB = tmp;  // sA = latest (iter 2*(pr+1))
    }

    dev_tail(bid, tid, (int*)shu64, sA, out + NM, counters);
    grid.sync();
    if (bid == 0) dev_valid(tid, counters, out + NM + (size_t)NI * HW);
}

// ===================== fallback kernels (same geometry, same numerics) ======
__global__ __launch_bounds__(TPB) void fb_setup(const float* __restrict__ seg,
    const float* __restrict__ feat, const float* __restrict__ x,
    const float* __restrict__ targets, unsigned char* __restrict__ state,
    float* __restrict__ crfk, unsigned long long* __restrict__ packed,
    int* __restrict__ counters) {
    dev_setup(blockIdx.x * TPB + threadIdx.x, seg, feat, x, targets, state, crfk,
              packed, counters);
}
__global__ __launch_bounds__(TPB) void fb_diou(const unsigned long long* __restrict__ packed,
    const int* __restrict__ labels, float* __restrict__ diou) {
    __shared__ unsigned long long sh[WORDS];
    dev_diou(blockIdx.x, threadIdx.x, sh, packed, labels, diou);
}
__global__ __launch_bounds__(TPB) void fb_compm(const float* __restrict__ diou,
                                                float* __restrict__ compm) {
    __shared__ float red[NM];
    dev_compm(blockIdx.x, threadIdx.x, red, diou, compm);
}
__global__ __launch_bounds__(TPB) void fb_coef(const float* __restrict__ diou,
    const float* __restrict__ compm, const float* __restrict__ scores_in,
    float* __restrict__ out) {
    __shared__ float red[NM];
    dev_coef(blockIdx.x, threadIdx.x, red, diou, compm, scores_in, out);
}
__global__ __launch_bounds__(TPB) void fb_pair(const unsigned char* __restrict__ sIn,
    unsigned char* __restrict__ sOut, const float* __restrict__ crfk) {
    __shared__ uint32_t mid32[19 * 32];
    dev_crf_pair(blockIdx.x, threadIdx.x, mid32, sIn, sOut, crfk);
}
__global__ __launch_bounds__(TPB) void fb_tail(const unsigned char* __restrict__ s,
    float* __restrict__ outMasks, int* __restrict__ counters) {
    __shared__ int red[TPB];
    dev_tail(blockIdx.x, threadIdx.x, red, s, outMasks, counters);
}
__global__ __launch_bounds__(TPB) void fb_valid(const int* __restrict__ counters,
                                                float* __restrict__ outValid) {
    dev_valid(threadIdx.x, counters, outValid);
}

extern "C" void kernel_launch(void* const* d_in, const int* in_sizes, int n_in,
                              void* d_out, int out_size, void* d_ws, size_t ws_size,
                              hipStream_t stream) {
    const float* seg = (const float*)d_in[0];
    const float* cate_scores = (const float*)d_in[1];
    const float* feat = (const float*)d_in[2];
    const float* x = (const float*)d_in[3];
    const float* targets = (const float*)d_in[4];
    const int* labels = (const int*)d_in[5];
    float* out = (float*)d_out;
    char* ws = (char*)d_ws;

    void* args[] = {(void*)&seg, (void*)&cate_scores, (void*)&feat, (void*)&x,
                    (void*)&targets, (void*)&labels, (void*)&out, (void*)&ws};
    hipError_t rc = hipLaunchCooperativeKernel((const void*)mega_kernel, dim3(GRID),
                                               dim3(TPB), args, 0, stream);
    if (rc != hipSuccess) {
        (void)hipGetLastError();  // clear sticky error; deterministic fallback below
        unsigned char* stateA = (unsigned char*)(ws + OFF_STATE_A);
        unsigned char* stateB = (unsigned char*)(ws + OFF_STATE_B);
        unsigned long long* packed = (unsigned long long*)(ws + OFF_PACKED);
        float* diou = (float*)(ws + OFF_DIOU);
        float* compm = (float*)(ws + OFF_COMPM);
        int* counters = (int*)(ws + OFF_CNT);
        float* crfk = (float*)(ws + OFF_CRFK);

        fb_setup<<<GRID, TPB, 0, stream>>>(seg, feat, x, targets, stateA, crfk,
                                           packed, counters);
        fb_diou<<<NM, TPB, 0, stream>>>(packed, labels, diou);
        fb_compm<<<NM, TPB, 0, stream>>>(diou, compm);
        fb_coef<<<NM, TPB, 0, stream>>>(diou, compm, cate_scores, out);
        unsigned char* sIn = stateA;
        unsigned char* sOut = stateB;
        for (int pr = 0; pr < 5; ++pr) {
            fb_pair<<<GRID, TPB, 0, stream>>>(sIn, sOut, crfk);
            unsigned char* tmp = sIn; sIn = sOut; sOut = tmp;
        }
        fb_tail<<<GRID, TPB, 0, stream>>>(sIn, out + NM, counters);
        fb_valid<<<1, TPB, 0, stream>>>(counters, out + NM + (size_t)NI * HW);
    }
}

// Round 7
// 337.752 us; speedup vs baseline: 2.3494x; 2.3494x over previous
//
#include <hip/hip_runtime.h>
#include <stdint.h>

#define HW 16384
#define NI 64
#define NM 256
#define WORDS 256

// ws layout (~1.8 MB used)
#define OFF_STATE  0u            // 1 MB state bytes
#define OFF_PACKED (1u << 20)    // 512 KB bit-packed masks [word][mask]
#define OFF_DIOUT  0x180000u     // 256 KB diou TRANSPOSED: diouT[col][row]
#define OFF_COMPM  0x1C0000u     // 1 KB
#define OFF_CNT    0x1C1000u     // 64 counters + done ticket at [64]

// ---------------- setup: state init + mask pack + counter zero --------------
__global__ __launch_bounds__(256) void setup_kernel(
    const float* __restrict__ seg, const float* __restrict__ x,
    const float* __restrict__ targets, unsigned char* __restrict__ state,
    unsigned long long* __restrict__ packed, int* __restrict__ counters) {
    #pragma clang fp contract(off)
    const int gid = blockIdx.x * 256 + threadIdx.x;  // 512 blocks -> 131072 threads
    for (int u = gid; u < 262144; u += 131072) {
        const int px0 = u * 4;
        const float4 xv = *(const float4*)(x + px0);
        const float4 tv = *(const float4*)(targets + px0);
        float xs[4] = {xv.x, xv.y, xv.z, xv.w};
        float ts[4] = {tv.x, tv.y, tv.z, tv.w};
        uint32_t st = 0;
        for (int j = 0; j < 4; ++j) {
            float xt = xs[j] * ts[j];
            int b1 = (xt > 0.5f) ? 1 : 0;
            int tb = (ts[j] > 0.5f) ? 1 : 0;
            st |= (uint32_t)(b1 | ((b1 ^ 1) << 1) | (tb << 2)) << (8 * j);
        }
        *(uint32_t*)(state + px0) = st;
    }
    // pack: 2048 waves x 32 (mask, word) pairs
    const int wv = gid >> 6, lane = gid & 63;
    for (int t = 0; t < 32; ++t) {
        int gwi = wv * 32 + t;       // [0, 65536)
        int i = gwi >> 8, w = gwi & 255;
        float v = seg[(size_t)i * HW + w * 64 + lane];
        unsigned long long m = __ballot(v > 0.5f);
        if (lane == 0) packed[w * NM + i] = m;
    }
    if (gid < NI + 1) counters[gid] = 0;  // [64] = done ticket
}

// ---------------- fused diou (column-wise) + compm --------------------------
// Block j computes diou column j (d[i][j], i=tid) then compm[j] immediately.
__global__ __launch_bounds__(256) void diou_compm_kernel(
    const unsigned long long* __restrict__ packed, const int* __restrict__ labels,
    float* __restrict__ diouT, float* __restrict__ compm) {
    #pragma clang fp contract(off)
    __shared__ unsigned long long colj[WORDS];
    __shared__ float red[NM];
    const int j = blockIdx.x, i = threadIdx.x;
    colj[i] = packed[i * NM + j];
    __syncthreads();
    int inter = 0, si = 0, sj = 0;
    for (int w = 0; w < WORDS; ++w) {
        unsigned long long a = colj[w];            // mask j word w
        unsigned long long b = packed[w * NM + i]; // mask i word w (coalesced)
        inter += __popcll(a & b);
        sj += __popcll(a);
        si += __popcll(b);
    }
    float d = 0.0f;
    if (j > i && labels[i] == labels[j]) {         // triu: row i < col j
        float u = (float)(si + sj - inter);        // exact integers in f32
        d = (float)inter / u;
    }
    diouT[j * NM + i] = d;                         // transposed, coalesced
    red[i] = d;
    __syncthreads();
    for (int off = 128; off > 0; off >>= 1) {
        if (i < off) red[i] = fmaxf(red[i], red[i + off]);
        __syncthreads();
    }
    if (i == 0) {
        float m = red[0];
        float t = m * m;
        compm[j] = expf(-2.0f * t);
    }
}

// ---------------- CRF mega: coef + 10 iterations + masks + counts + valid ---
// 512 blocks (64 img x 8 tiles of 16 rows) x 1024 threads.
// Iter t computes rows [max(0,r0-9+t), min(128,r0+25-t)) — every tap of iter t
// lies inside iter t-1's computed range, so values == full-sweep (bit-exact).
// Weights recomputed each iteration from LDS-staged fm = feat+10 (exact: same
// single rounded add as reference's fm).
const float SP[9] = {0,0,0,0,0,0,0,0,0};  // unused placeholder (kept for clarity)

template <bool G, bool FINAL>
__device__ __forceinline__ int crf_sweep(
    int tid, int lo, int hi, int s_lo, int f_lo,
    const unsigned char* __restrict__ gs,   // global state (img base) if G
    const uint32_t* __restrict__ srcw,      // LDS src state words if !G
    uint32_t* __restrict__ dstw,            // LDS dst state words if !FINAL
    const float* __restrict__ fm0, const float* __restrict__ fm1,
    const float* __restrict__ fm2,
    float* __restrict__ om) {               // masks out (img base) if FINAL
    #pragma clang fp contract(off)
    const float l45 = 0.7985076962177716f;  // -log(0.45f)
    const float l55 = 0.5978370007556204f;  // -log(0.55f)
    int cnt = 0;
    const int p = lo * 128 + tid * 8;       // 8-px strip, single pass (<=4352 px)
    if (p < hi * 128) {
        const int y = p >> 7, xc = p & 127;
        // center fm (3 ch x 8)
        float cf0[8], cf1[8], cf2[8];
        {
            int cb = (y - f_lo) * 128 + xc;
            float4 a, b;
            a = *(const float4*)&fm0[cb]; b = *(const float4*)&fm0[cb + 4];
            cf0[0]=a.x; cf0[1]=a.y; cf0[2]=a.z; cf0[3]=a.w; cf0[4]=b.x; cf0[5]=b.y; cf0[6]=b.z; cf0[7]=b.w;
            a = *(const float4*)&fm1[cb]; b = *(const float4*)&fm1[cb + 4];
            cf1[0]=a.x; cf1[1]=a.y; cf1[2]=a.z; cf1[3]=a.w; cf1[4]=b.x; cf1[5]=b.y; cf1[6]=b.z; cf1[7]=b.w;
            a = *(const float4*)&fm2[cb]; b = *(const float4*)&fm2[cb + 4];
            cf2[0]=a.x; cf2[1]=a.y; cf2[2]=a.z; cf2[3]=a.w; cf2[4]=b.x; cf2[5]=b.y; cf2[6]=b.z; cf2[7]=b.w;
        }
        float a0[8], a1[8];
        #pragma unroll
        for (int j = 0; j < 8; ++j) { a0[j] = 0.0f; a1[j] = 0.0f; }
        uint32_t csw0 = 0, csw1 = 0;
        #pragma unroll
        for (int dy = -1; dy <= 1; ++dy) {
            int ny = y + dy;
            if ((unsigned)ny < 128u) {
                int fr = (ny - f_lo) * 128;
                float v0[10], v1[10], v2[10];
                {
                    float4 a, b;
                    a = *(const float4*)&fm0[fr + xc]; b = *(const float4*)&fm0[fr + xc + 4];
                    v0[0] = (xc > 0) ? fm0[fr + xc - 1] : 0.0f;
                    v0[1]=a.x; v0[2]=a.y; v0[3]=a.z; v0[4]=a.w; v0[5]=b.x; v0[6]=b.y; v0[7]=b.z; v0[8]=b.w;
                    v0[9] = (xc < 120) ? fm0[fr + xc + 8] : 0.0f;
                    a = *(const float4*)&fm1[fr + xc]; b = *(const float4*)&fm1[fr + xc + 4];
                    v1[0] = (xc > 0) ? fm1[fr + xc - 1] : 0.0f;
                    v1[1]=a.x; v1[2]=a.y; v1[3]=a.z; v1[4]=a.w; v1[5]=b.x; v1[6]=b.y; v1[7]=b.z; v1[8]=b.w;
                    v1[9] = (xc < 120) ? fm1[fr + xc + 8] : 0.0f;
                    a = *(const float4*)&fm2[fr + xc]; b = *(const float4*)&fm2[fr + xc + 4];
                    v2[0] = (xc > 0) ? fm2[fr + xc - 1] : 0.0f;
                    v2[1]=a.x; v2[2]=a.y; v2[3]=a.z; v2[4]=a.w; v2[5]=b.x; v2[6]=b.y; v2[7]=b.z; v2[8]=b.w;
                    v2[9] = (xc < 120) ? fm2[fr + xc + 8] : 0.0f;
                }
                // state bytes for cols xc-1 .. xc+8 via 4 aligned word loads
                uint32_t sw0, sw1, sw2, sw3;
                if (G) {
                    const uint32_t* gr = (const uint32_t*)(gs + ny * 128);
                    int wx = xc >> 2;
                    sw0 = (xc > 0) ? gr[wx - 1] : 0u;
                    sw1 = gr[wx];
                    sw2 = gr[wx + 1];
                    sw3 = (xc < 120) ? gr[wx + 2] : 0u;
                } else {
                    const uint32_t* lr = srcw + (ny - s_lo) * 32;
                    int wx = xc >> 2;
                    sw0 = (xc > 0) ? lr[wx - 1] : 0u;
                    sw1 = lr[wx];
                    sw2 = lr[wx + 1];
                    sw3 = (xc < 120) ? lr[wx + 2] : 0u;
                }
                if (dy == 0) { csw0 = sw1; csw1 = sw2; }
                unsigned char sb[10];
                sb[0] = sw0 >> 24;
                sb[1] = sw1 & 0xff; sb[2] = (sw1 >> 8) & 0xff; sb[3] = (sw1 >> 16) & 0xff; sb[4] = sw1 >> 24;
                sb[5] = sw2 & 0xff; sb[6] = (sw2 >> 8) & 0xff; sb[7] = (sw2 >> 16) & 0xff; sb[8] = sw2 >> 24;
                sb[9] = sw3 & 0xff;
                #pragma unroll
                for (int dx = -1; dx <= 1; ++dx) {
                    const float spk = (float)(dy * dy + dx * dx) / 1800.0f;  // exact const fold
                    #pragma unroll
                    for (int j = 0; j < 8; ++j) {
                        int xx = xc + j + dx;
                        if ((unsigned)xx < 128u) {
                            const int m = j + dx + 1;  // 0..9, static
                            float d0 = v0[m] - cf0[j];
                            float d1 = v1[m] - cf1[j];
                            float d2 = v2[m] - cf2[j];
                            float ss = d0 * d0;
                            ss = ss + d1 * d1;
                            ss = ss + d2 * d2;
                            float color = (-ss) / 0.5f;
                            float kw = 3.0f * expf(color - spk);
                            unsigned char sq = sb[m];
                            float lx1 = (sq & 1) ? l55 : l45;
                            float lx0 = (sq & 2) ? l55 : l45;
                            float t1 = lx1 * kw;   // mul then add (numpy order)
                            float t0 = lx0 * kw;
                            a1[j] = a1[j] + t1;
                            a0[j] = a0[j] + t0;
                        }
                    }
                }
            }
        }
        // epilogue (proven exact sequence)
        uint32_t ow0 = 0, ow1 = 0;
        float mv[8];
        #pragma unroll
        for (int j = 0; j < 8; ++j) {
            unsigned char sc = (unsigned char)(((j < 4) ? (csw0 >> (8 * j)) : (csw1 >> (8 * (j - 4)))) & 0xffu);
            float tval = (sc & 4) ? 1.0f : 0.0f;
            float e1 = expf(-a1[j]);
            float e0 = expf(-a0[j]);
            float m1 = e1 * tval;
            float f1 = m1 + 1e-6f;
            float f0 = e0 + 1e-6f;
            float den = f0 + f1;
            float r1 = f1 / den;
            float r0v = f0 / den;
            int s1 = (r1 > 0.5f) ? 1 : 0;
            int s0 = (r0v > 0.5f) ? 1 : 0;
            if (FINAL) {
                cnt += s1;
                mv[j] = (float)s1;
            } else {
                uint32_t byte = (uint32_t)(s1 | (s0 << 1) | (sc & 4));
                if (j < 4) ow0 |= byte << (8 * j); else ow1 |= byte << (8 * (j - 4));
            }
        }
        if (FINAL) {
            *(float4*)(om + p) = make_float4(mv[0], mv[1], mv[2], mv[3]);
            *(float4*)(om + p + 4) = make_float4(mv[4], mv[5], mv[6], mv[7]);
        } else {
            uint32_t* dst = dstw + (y - s_lo) * 32 + (xc >> 2);
            dst[0] = ow0;
            dst[1] = ow1;
        }
    }
    return cnt;
}

__global__ __launch_bounds__(1024) void crf_mega_kernel(
    const float* __restrict__ feat, const float* __restrict__ scores,
    const float* __restrict__ diouT, const float* __restrict__ compm,
    const unsigned char* __restrict__ stateA, float* __restrict__ out,
    int* __restrict__ counters) {
    #pragma clang fp contract(off)
    __shared__ float fmL[3][36 * 128];      // 55296 B
    __shared__ uint32_t stL[2][34 * 32];    // 8704 B  (total 64000 B)
    const int tid = threadIdx.x, bid = blockIdx.x;
    const int img = bid >> 3, tile = bid & 7;
    const int r0 = tile * 16;

    // ---- NMS coef (blocks 0..255, column bid) — reuses stL as scratch ----
    if (bid < NM) {
        float* red = (float*)&stL[0][0];
        if (tid < NM) {
            float d = diouT[bid * NM + tid];   // column bid of diou
            float dd = d * d;
            float dec = expf(-2.0f * dd);
            red[tid] = dec / compm[tid];
        }
        __syncthreads();
        for (int off = 128; off > 0; off >>= 1) {
            if (tid < off) red[tid] = fminf(red[tid], red[tid + off]);
            __syncthreads();
        }
        if (tid == 0) out[bid] = scores[bid] * red[0];
        __syncthreads();   // before stL reuse as state
    }

    // ---- stage fm = feat + 10 for window rows ----
    const int f_lo = (r0 - 10 < 0) ? 0 : r0 - 10;
    const int f_hi = (r0 + 26 > 128) ? 128 : r0 + 26;
    for (int ch = 0; ch < 3; ++ch) {
        const float* src = feat + ((size_t)img * 3 + ch) * HW + f_lo * 128;
        const int n = (f_hi - f_lo) * 128;
        for (int i = tid * 4; i < n; i += 4096) {
            float4 v = *(const float4*)(src + i);
            *(float4*)&fmL[ch][i] = make_float4(v.x + 10.0f, v.y + 10.0f,
                                                v.z + 10.0f, v.w + 10.0f);
        }
    }
    __syncthreads();

    // ---- 10 iterations with shrinking halo ----
    const int s_lo = (r0 - 9 < 0) ? 0 : r0 - 9;
    const unsigned char* gs = stateA + (size_t)img * HW;
    float* om = out + NM + (size_t)img * HW;
    {
        int lo = (r0 - 9 < 0) ? 0 : r0 - 9;
        int hi = (r0 + 25 > 128) ? 128 : r0 + 25;
        crf_sweep<true, false>(tid, lo, hi, s_lo, f_lo, gs, nullptr, &stL[0][0],
                               fmL[0], fmL[1], fmL[2], nullptr);
        __syncthreads();
    }
    for (int t = 1; t < 9; ++t) {
        int lo = r0 - 9 + t; if (lo < 0) lo = 0;
        int hi = r0 + 25 - t; if (hi > 128) hi = 128;
        crf_sweep<false, false>(tid, lo, hi, s_lo, f_lo, nullptr,
                                &stL[(t - 1) & 1][0], &stL[t & 1][0],
                                fmL[0], fmL[1], fmL[2], nullptr);
        __syncthreads();
    }
    int cnt = crf_sweep<false, true>(tid, r0, r0 + 16, s_lo, f_lo, nullptr,
                                     &stL[0][0], nullptr,
                                     fmL[0], fmL[1], fmL[2], om);
    __syncthreads();

    // ---- counts + valid (atomic ticket: last block writes valid) ----
    int* cred = (int*)&stL[1][0];
    cred[tid] = cnt;
    __syncthreads();
    for (int off = 512; off > 0; off >>= 1) {
        if (tid < off) cred[tid] += cred[tid + off];
        __syncthreads();
    }
    int* flag = (int*)&stL[0][0];
    if (tid == 0) {
        atomicAdd(&counters[img], cred[0]);
        __threadfence();
        int old = atomicAdd(&counters[NI], 1);
        flag[0] = (old == 511) ? 1 : 0;
    }
    __syncthreads();
    if (flag[0] && tid < NI) {
        int c = atomicAdd(&counters[tid], 0);   // coherent device-scope read
        // 16384*0.05 = 819.2, 16384*0.95 = 15564.8; counts are integers
        out[NM + (size_t)NI * HW + tid] = (c >= 820 && c <= 15564) ? 1.0f : 0.0f;
    }
}

extern "C" void kernel_launch(void* const* d_in, const int* in_sizes, int n_in,
                              void* d_out, int out_size, void* d_ws, size_t ws_size,
                              hipStream_t stream) {
    const float* seg = (const float*)d_in[0];
    const float* cate_scores = (const float*)d_in[1];
    const float* feat = (const float*)d_in[2];
    const float* x = (const float*)d_in[3];
    const float* targets = (const float*)d_in[4];
    const int* labels = (const int*)d_in[5];
    float* out = (float*)d_out;
    char* ws = (char*)d_ws;

    unsigned char* state = (unsigned char*)(ws + OFF_STATE);
    unsigned long long* packed = (unsigned long long*)(ws + OFF_PACKED);
    float* diouT = (float*)(ws + OFF_DIOUT);
    float* compm = (float*)(ws + OFF_COMPM);
    int* counters = (int*)(ws + OFF_CNT);

    setup_kernel<<<512, 256, 0, stream>>>(seg, x, targets, state, packed, counters);
    diou_compm_kernel<<<NM, 256, 0, stream>>>(packed, labels, diouT, compm);
    crf_mega_kernel<<<512, 1024, 0, stream>>>(feat, cate_scores, diouT, compm,
                                              state, out, counters);
}

// Round 8
// 228.171 us; speedup vs baseline: 3.4777x; 1.4803x over previous
//
#include <hip/hip_runtime.h>
#include <stdint.h>

#define HW 16384
#define NI 64
#define NM 256
#define WORDS 256

// ws layout (~3 MB used)
#define OFF_STATE  0u            // 1 MB state bytes (iter 0)
#define OFF_STATE2 (1u << 20)    // 1 MB state bytes (iter 5 handoff)
#define OFF_PACKED (2u << 20)    // 512 KB bit-packed masks [word][mask]
#define OFF_DIOUT  0x280000u     // 256 KB diou transposed diouT[col][row]
#define OFF_COMPM  0x2C0000u
#define OFF_CNT    0x2C1000u     // 64 counters + done ticket at [64]

// ---------------- setup: state init + mask pack + counter zero (proven) -----
__global__ __launch_bounds__(256) void setup_kernel(
    const float* __restrict__ seg, const float* __restrict__ x,
    const float* __restrict__ targets, unsigned char* __restrict__ state,
    unsigned long long* __restrict__ packed, int* __restrict__ counters) {
    #pragma clang fp contract(off)
    const int gid = blockIdx.x * 256 + threadIdx.x;
    for (int u = gid; u < 262144; u += 131072) {
        const int px0 = u * 4;
        const float4 xv = *(const float4*)(x + px0);
        const float4 tv = *(const float4*)(targets + px0);
        float xs[4] = {xv.x, xv.y, xv.z, xv.w};
        float ts[4] = {tv.x, tv.y, tv.z, tv.w};
        uint32_t st = 0;
        for (int j = 0; j < 4; ++j) {
            float xt = xs[j] * ts[j];
            int b1 = (xt > 0.5f) ? 1 : 0;
            int tb = (ts[j] > 0.5f) ? 1 : 0;
            st |= (uint32_t)(b1 | ((b1 ^ 1) << 1) | (tb << 2)) << (8 * j);
        }
        *(uint32_t*)(state + px0) = st;
    }
    const int wv = gid >> 6, lane = gid & 63;
    for (int t = 0; t < 32; ++t) {
        int gwi = wv * 32 + t;
        int i = gwi >> 8, w = gwi & 255;
        float v = seg[(size_t)i * HW + w * 64 + lane];
        unsigned long long m = __ballot(v > 0.5f);
        if (lane == 0) packed[w * NM + i] = m;
    }
    if (gid < NI + 1) counters[gid] = 0;
}

// ---------------- fused diou + compm (proven R7) ----------------------------
__global__ __launch_bounds__(256) void diou_compm_kernel(
    const unsigned long long* __restrict__ packed, const int* __restrict__ labels,
    float* __restrict__ diouT, float* __restrict__ compm) {
    #pragma clang fp contract(off)
    __shared__ unsigned long long colj[WORDS];
    __shared__ float red[NM];
    const int j = blockIdx.x, i = threadIdx.x;
    colj[i] = packed[i * NM + j];
    __syncthreads();
    int inter = 0, si = 0, sj = 0;
    for (int w = 0; w < WORDS; ++w) {
        unsigned long long a = colj[w];
        unsigned long long b = packed[w * NM + i];
        inter += __popcll(a & b);
        sj += __popcll(a);
        si += __popcll(b);
    }
    float d = 0.0f;
    if (j > i && labels[i] == labels[j]) {
        float u = (float)(si + sj - inter);
        d = (float)inter / u;
    }
    diouT[j * NM + i] = d;
    red[i] = d;
    __syncthreads();
    for (int off = 128; off > 0; off >>= 1) {
        if (i < off) red[i] = fmaxf(red[i], red[i + off]);
        __syncthreads();
    }
    if (i == 0) {
        float m = red[0];
        float t = m * m;
        compm[j] = expf(-2.0f * t);
    }
}

// ---------------- CRF: 5 iterations per launch, LDS-resident planes ---------
// 512 blocks = 64 img x 8 tiles of 16 rows; 768 threads; window 26 rows.
// Symmetry (exact in f32): kw[k][p] == kw[8-k][p+off(k)]; center kw == 3.0f.
// So only planes k=0..3 are stored. Sweep s computes rows
// [max(0,r0-4+s), min(128,r0+20-s)) — taps always inside prior sweep's range,
// so values are bit-identical to full-image sweeps (proven halo argument).

__device__ __forceinline__ int sweep5(
    int tid, int lo, int hi, int w0,
    const uint32_t* __restrict__ srcw,   // LDS state words (26x32)
    uint32_t* __restrict__ dstw,         // LDS dst (or null)
    uint32_t* __restrict__ gdst,         // global word dst (phase-A final, or null)
    float* __restrict__ om,              // masks out img base (phase-B final, or null)
    const float* __restrict__ plane) {
    #pragma clang fp contract(off)
    const float l45 = 0.7985076962177716f;  // -log(0.45f)
    const float l55 = 0.5978370007556204f;  // -log(0.55f)
    int cnt = 0;
    const int np = (hi - lo) * 32;
    if (tid < np) {
        const int p = lo * 128 + tid * 4;
        const int y = p >> 7, xc = p & 127, wx = xc >> 2;
        // state bytes for rows y-1,y,y+1 cols xc-1..xc+4
        unsigned char rb[3][6];
        #pragma unroll
        for (int r = 0; r < 3; ++r) {
            int ry = y + r - 1;
            if ((unsigned)ry < 128u) {
                const uint32_t* lr = srcw + (ry - w0) * 32;
                uint32_t wm = (xc > 0) ? lr[wx - 1] : 0u;
                uint32_t w0w = lr[wx];
                uint32_t wp = (xc < 124) ? lr[wx + 1] : 0u;
                rb[r][0] = wm >> 24;
                rb[r][1] = w0w & 0xff; rb[r][2] = (w0w >> 8) & 0xff;
                rb[r][3] = (w0w >> 16) & 0xff; rb[r][4] = w0w >> 24;
                rb[r][5] = wp & 0xff;
            } else {
                #pragma unroll
                for (int m = 0; m < 6; ++m) rb[r][m] = 0;
            }
        }
        float a0[4] = {0.f, 0.f, 0.f, 0.f}, a1[4] = {0.f, 0.f, 0.f, 0.f};
        #pragma unroll
        for (int k = 0; k < 9; ++k) {
            const int dy = k / 3 - 1, dx = k % 3 - 1;
            const int ry = y + dy;
            if ((unsigned)ry < 128u) {
                const int kp = (k < 4) ? k : (8 - k);
                const int prow = ((k < 4) ? y : ry) - w0;
                #pragma unroll
                for (int j = 0; j < 4; ++j) {
                    const int xx = xc + j + dx;
                    if ((unsigned)xx < 128u) {
                        float kw;
                        if (k == 4) kw = 3.0f;
                        else {
                            const int pcol = (k < 4) ? (xc + j) : xx;
                            kw = plane[kp * 3328 + prow * 128 + pcol];
                        }
                        unsigned char sq = rb[dy + 1][j + dx + 1];
                        float lx1 = (sq & 1) ? l55 : l45;
                        float lx0 = (sq & 2) ? l55 : l45;
                        float t1 = lx1 * kw;   // mul then add (numpy order)
                        float t0 = lx0 * kw;
                        a1[j] = a1[j] + t1;
                        a0[j] = a0[j] + t0;
                    }
                }
            }
        }
        // epilogue (proven exact sequence)
        uint32_t ow = 0;
        float mv[4];
        int c1 = 0;
        #pragma unroll
        for (int j = 0; j < 4; ++j) {
            unsigned char sc = rb[1][j + 1];
            float tval = (sc & 4) ? 1.0f : 0.0f;
            float e1 = expf(-a1[j]);
            float e0 = expf(-a0[j]);
            float m1 = e1 * tval;
            float f1 = m1 + 1e-6f;
            float f0 = e0 + 1e-6f;
            float den = f0 + f1;
            float r1 = f1 / den;
            float r0v = f0 / den;
            int s1 = (r1 > 0.5f) ? 1 : 0;
            int s0 = (r0v > 0.5f) ? 1 : 0;
            if (om) { mv[j] = (float)s1; c1 += s1; }
            ow |= (uint32_t)(s1 | (s0 << 1) | (sc & 4)) << (8 * j);
        }
        if (dstw) dstw[(y - w0) * 32 + wx] = ow;
        else if (gdst) gdst[y * 32 + wx] = ow;
        else {
            *(float4*)(om + p) = make_float4(mv[0], mv[1], mv[2], mv[3]);
            cnt = c1;
        }
    }
    return cnt;
}

template <bool FIRST>
__global__ __launch_bounds__(768, 6) void crf5_kernel(
    const float* __restrict__ feat, const float* __restrict__ scores,
    const float* __restrict__ diouT, const float* __restrict__ compm,
    const unsigned char* __restrict__ gsrc, unsigned char* __restrict__ gdst2,
    float* __restrict__ out, int* __restrict__ counters) {
    #pragma clang fp contract(off)
    __shared__ float plane[4 * 3328];     // 53248 B: planes k=0..3, 26 rows
    __shared__ uint32_t stw[2][26 * 32];  // 6656 B ping-pong state
    const int tid = threadIdx.x, bid = blockIdx.x;
    const int img = bid >> 3, r0 = (bid & 7) * 16;
    const int w0 = r0 - 5;

    // ---- coef (phase A only, blocks 0..255) — plane area as scratch -------
    if (FIRST && bid < NM) {
        float* red = plane;
        if (tid < NM) {
            float d = diouT[bid * NM + tid];
            float dd = d * d;
            float dec = expf(-2.0f * dd);
            red[tid] = dec / compm[tid];
        }
        __syncthreads();
        for (int off = 128; off > 0; off >>= 1) {
            if (tid < off) red[tid] = fminf(red[tid], red[tid + off]);
            __syncthreads();
        }
        if (tid == 0) out[bid] = scores[bid] * red[0];
        __syncthreads();
    }

    // ---- plane precompute (once; reused by all 5 sweeps) -------------------
    const float* fb = feat + (size_t)img * 3 * HW;
    for (int qi = tid; qi < 4 * 832; qi += 768) {
        const int k = qi >> 5 == 0 ? 0 : qi / 832;  // plane id 0..3
        const int rem = qi - k * 832;
        const int rel = rem >> 5, qc = (rem & 31) << 2;
        const int gy = w0 + rel;
        if ((unsigned)gy < 128u) {
            const int dy = (k < 3) ? -1 : 0;
            const int dx = (k < 3) ? (k - 1) : -1;
            const int ny = gy + dy;
            float res[4];
            #pragma unroll
            for (int j = 0; j < 4; ++j) {
                const int col = qc + j, nx = col + dx;
                float kw = 0.0f;
                if ((unsigned)ny < 128u && (unsigned)nx < 128u) {
                    const int pp = gy * 128 + col, qq = ny * 128 + nx;
                    float c0 = fb[pp] + 10.0f;
                    float c1 = fb[HW + pp] + 10.0f;
                    float c2 = fb[2 * HW + pp] + 10.0f;
                    float u0 = fb[qq] + 10.0f;
                    float u1 = fb[HW + qq] + 10.0f;
                    float u2 = fb[2 * HW + qq] + 10.0f;
                    float d0 = u0 - c0, d1 = u1 - c1, d2 = u2 - c2;
                    float ss = d0 * d0;
                    ss = ss + d1 * d1;
                    ss = ss + d2 * d2;
                    float color = (-ss) / 0.5f;
                    float sp = (float)(dy * dy + dx * dx) / 1800.0f;
                    kw = 3.0f * expf(color - sp);
                }
                res[j] = kw;
            }
            *(float4*)&plane[k * 3328 + rel * 128 + qc] =
                make_float4(res[0], res[1], res[2], res[3]);
        }
    }

    // ---- load window state (26 rows) from global ---------------------------
    for (int idx = tid; idx < 832; idx += 768) {
        const int rel = idx >> 5, gy = w0 + rel;
        if ((unsigned)gy < 128u)
            stw[0][idx] = ((const uint32_t*)(gsrc + (size_t)img * HW + gy * 128))[idx & 31];
    }
    __syncthreads();

    // ---- 5 sweeps ----------------------------------------------------------
    int sA = 0, cnt = 0;
    for (int s = 0; s < 5; ++s) {
        int lo = r0 - 4 + s; if (lo < 0) lo = 0;
        int hi = r0 + 20 - s; if (hi > 128) hi = 128;
        const bool last = (s == 4);
        uint32_t* dst = last ? nullptr : &stw[sA ^ 1][0];
        uint32_t* gw = (last && FIRST) ? (uint32_t*)(gdst2 + (size_t)img * HW) : nullptr;
        float* om = (last && !FIRST) ? (out + NM + (size_t)img * HW) : nullptr;
        cnt += sweep5(tid, lo, hi, w0, &stw[sA][0], dst, gw, om, plane);
        __syncthreads();
        if (!last) sA ^= 1;
    }

    // ---- phase B tail: counts + valid (proven ticket) ----------------------
    if (!FIRST) {
        int* cred = (int*)plane;
        cred[tid] = cnt;
        __syncthreads();
        if (tid < 256) cred[tid] = cred[tid] + cred[tid + 256] + cred[tid + 512];
        __syncthreads();
        for (int off = 128; off > 0; off >>= 1) {
            if (tid < off) cred[tid] += cred[tid + off];
            __syncthreads();
        }
        int* flag = (int*)&stw[0][0];
        if (tid == 0) {
            atomicAdd(&counters[img], cred[0]);
            __threadfence();
            int old = atomicAdd(&counters[NI], 1);
            flag[0] = (old == 511) ? 1 : 0;
        }
        __syncthreads();
        if (flag[0] && tid < NI) {
            int c = atomicAdd(&counters[tid], 0);
            // 16384*0.05 = 819.2, 16384*0.95 = 15564.8; counts are integers
            out[NM + (size_t)NI * HW + tid] = (c >= 820 && c <= 15564) ? 1.0f : 0.0f;
        }
    }
}

extern "C" void kernel_launch(void* const* d_in, const int* in_sizes, int n_in,
                              void* d_out, int out_size, void* d_ws, size_t ws_size,
                              hipStream_t stream) {
    const float* seg = (const float*)d_in[0];
    const float* cate_scores = (const float*)d_in[1];
    const float* feat = (const float*)d_in[2];
    const float* x = (const float*)d_in[3];
    const float* targets = (const float*)d_in[4];
    const int* labels = (const int*)d_in[5];
    float* out = (float*)d_out;
    char* ws = (char*)d_ws;

    unsigned char* state = (unsigned char*)(ws + OFF_STATE);
    unsigned char* state2 = (unsigned char*)(ws + OFF_STATE2);
    unsigned long long* packed = (unsigned long long*)(ws + OFF_PACKED);
    float* diouT = (float*)(ws + OFF_DIOUT);
    float* compm = (float*)(ws + OFF_COMPM);
    int* counters = (int*)(ws + OFF_CNT);

    setup_kernel<<<512, 256, 0, stream>>>(seg, x, targets, state, packed, counters);
    diou_compm_kernel<<<NM, 256, 0, stream>>>(packed, labels, diouT, compm);
    crf5_kernel<true><<<512, 768, 0, stream>>>(feat, cate_scores, diouT, compm,
                                               state, state2, out, counters);
    crf5_kernel<false><<<512, 768, 0, stream>>>(feat, cate_scores, diouT, compm,
                                                state2, nullptr, out, counters);
}

// Round 9
// 215.705 us; speedup vs baseline: 3.6787x; 1.0578x over previous
//
#include <hip/hip_runtime.h>
#include <stdint.h>

#define HW 16384
#define NI 64
#define NM 256
#define WORDS 256

// ws layout (~3 MB used)
#define OFF_STATE  0u            // 1 MB state bytes (iter 0)
#define OFF_STATE2 (1u << 20)    // 1 MB state bytes (iter 5 handoff)
#define OFF_PACKED (2u << 20)    // 512 KB bit-packed masks [word][mask]
#define OFF_DIOUT  0x280000u     // 256 KB diou transposed diouT[col][row]
#define OFF_COMPM  0x2C0000u
#define OFF_CNT    0x2C1000u     // 64 counters + done ticket at [64]

// ---------------- setup: state init + mask pack + counter zero (proven) -----
__global__ __launch_bounds__(256) void setup_kernel(
    const float* __restrict__ seg, const float* __restrict__ x,
    const float* __restrict__ targets, unsigned char* __restrict__ state,
    unsigned long long* __restrict__ packed, int* __restrict__ counters) {
    #pragma clang fp contract(off)
    const int gid = blockIdx.x * 256 + threadIdx.x;
    for (int u = gid; u < 262144; u += 131072) {
        const int px0 = u * 4;
        const float4 xv = *(const float4*)(x + px0);
        const float4 tv = *(const float4*)(targets + px0);
        float xs[4] = {xv.x, xv.y, xv.z, xv.w};
        float ts[4] = {tv.x, tv.y, tv.z, tv.w};
        uint32_t st = 0;
        for (int j = 0; j < 4; ++j) {
            float xt = xs[j] * ts[j];
            int b1 = (xt > 0.5f) ? 1 : 0;
            int tb = (ts[j] > 0.5f) ? 1 : 0;
            st |= (uint32_t)(b1 | ((b1 ^ 1) << 1) | (tb << 2)) << (8 * j);
        }
        *(uint32_t*)(state + px0) = st;
    }
    const int wv = gid >> 6, lane = gid & 63;
    for (int t = 0; t < 32; ++t) {
        int gwi = wv * 32 + t;
        int i = gwi >> 8, w = gwi & 255;
        float v = seg[(size_t)i * HW + w * 64 + lane];
        unsigned long long m = __ballot(v > 0.5f);
        if (lane == 0) packed[w * NM + i] = m;
    }
    if (gid < NI + 1) counters[gid] = 0;
}

// ---------------- fused diou + compm (proven) -------------------------------
__global__ __launch_bounds__(256) void diou_compm_kernel(
    const unsigned long long* __restrict__ packed, const int* __restrict__ labels,
    float* __restrict__ diouT, float* __restrict__ compm) {
    #pragma clang fp contract(off)
    __shared__ unsigned long long colj[WORDS];
    __shared__ float red[NM];
    const int j = blockIdx.x, i = threadIdx.x;
    colj[i] = packed[i * NM + j];
    __syncthreads();
    int inter = 0, si = 0, sj = 0;
    for (int w = 0; w < WORDS; ++w) {
        unsigned long long a = colj[w];
        unsigned long long b = packed[w * NM + i];
        inter += __popcll(a & b);
        sj += __popcll(a);
        si += __popcll(b);
    }
    float d = 0.0f;
    if (j > i && labels[i] == labels[j]) {
        float u = (float)(si + sj - inter);
        d = (float)inter / u;
    }
    diouT[j * NM + i] = d;
    red[i] = d;
    __syncthreads();
    for (int off = 128; off > 0; off >>= 1) {
        if (i < off) red[i] = fmaxf(red[i], red[i + off]);
        __syncthreads();
    }
    if (i == 0) {
        float m = red[0];
        float t = m * m;
        compm[j] = expf(-2.0f * t);
    }
}

// ---------------- CRF: 5 iterations/launch, kw in REGISTERS -----------------
// 512 blocks = 64 img x 8 tiles of 16 rows; 832 threads = 26 rows x 32 quads.
// Thread<->pixel binding fixed across sweeps -> each thread's 36 kw values
// (9 taps x 4 px) live in VGPRs, loaded once from the LDS planes (symmetry:
// kw[k][p] == kw[8-k][p+off(k)], exact in f32; center == 3.0f exactly).
// OOB taps have kw == 0 exactly -> branchless accumulate (a + lx*0 == a).
// Sweep s computes rows [max(0,r0-4+s), min(128,r0+20-s)) — taps always inside
// the prior sweep's computed range (proven halo argument, bit-exact).
template <bool FIRST>
__global__ __launch_bounds__(832, 6) void crf5_kernel(
    const float* __restrict__ feat, const float* __restrict__ scores,
    const float* __restrict__ diouT, const float* __restrict__ compm,
    const unsigned char* __restrict__ gsrc, unsigned char* __restrict__ gdst2,
    float* __restrict__ out, int* __restrict__ counters) {
    #pragma clang fp contract(off)
    __shared__ float plane[4 * 3328];     // 53248 B: planes k=0..3, 26 rows
    __shared__ uint32_t stw[2][26 * 32];  // 6656 B ping-pong state
    const int tid = threadIdx.x, bid = blockIdx.x;
    const int img = bid >> 3, r0 = (bid & 7) * 16;
    const int w0 = r0 - 5;

    // ---- coef (phase A, blocks 0..255) — plane as scratch ------------------
    if (FIRST && bid < NM) {
        float* red = plane;
        if (tid < NM) {
            float d = diouT[bid * NM + tid];
            float dd = d * d;
            float dec = expf(-2.0f * dd);
            red[tid] = dec / compm[tid];
        }
        __syncthreads();
        for (int off = 128; off > 0; off >>= 1) {
            if (tid < off) red[tid] = fminf(red[tid], red[tid + off]);
            __syncthreads();
        }
        if (tid == 0) out[bid] = scores[bid] * red[0];
        __syncthreads();
    }

    // ---- plane precompute: thread owns (row rel, quad) for all 4 planes ----
    const int rel = tid >> 5;             // 0..25
    const int xc = (tid & 31) * 4;
    const int y = w0 + rel;
    {
        if ((unsigned)y < 128u) {
            const float* fb = feat + (size_t)img * 3 * HW;
            const int pp = y * 128 + xc;
            float4 cv0 = *(const float4*)&fb[pp];
            float4 cv1 = *(const float4*)&fb[HW + pp];
            float4 cv2 = *(const float4*)&fb[2 * HW + pp];
            float c0[4] = {cv0.x + 10.0f, cv0.y + 10.0f, cv0.z + 10.0f, cv0.w + 10.0f};
            float c1[4] = {cv1.x + 10.0f, cv1.y + 10.0f, cv1.z + 10.0f, cv1.w + 10.0f};
            float c2[4] = {cv2.x + 10.0f, cv2.y + 10.0f, cv2.z + 10.0f, cv2.w + 10.0f};
            #pragma unroll
            for (int k = 0; k < 4; ++k) {
                const int dy = (k < 3) ? -1 : 0;
                const int dx = (k < 3) ? (k - 1) : -1;
                const int ny = y + dy;
                float res[4];
                #pragma unroll
                for (int j = 0; j < 4; ++j) {
                    const int nx = xc + j + dx;
                    float kwv = 0.0f;
                    if ((unsigned)ny < 128u && (unsigned)nx < 128u) {
                        const int qq = ny * 128 + nx;
                        float u0 = fb[qq] + 10.0f;
                        float u1 = fb[HW + qq] + 10.0f;
                        float u2 = fb[2 * HW + qq] + 10.0f;
                        float d0 = u0 - c0[j], d1 = u1 - c1[j], d2 = u2 - c2[j];
                        float ss = d0 * d0;
                        ss = ss + d1 * d1;
                        ss = ss + d2 * d2;
                        float color = (-ss) / 0.5f;
                        float sp = (float)(dy * dy + dx * dx) / 1800.0f;
                        kwv = 3.0f * expf(color - sp);
                    }
                    res[j] = kwv;
                }
                *(float4*)&plane[k * 3328 + rel * 128 + xc] =
                    make_float4(res[0], res[1], res[2], res[3]);
            }
        }
        // window state: one word per thread (26*32 == 832)
        if ((unsigned)y < 128u)
            stw[0][tid] = ((const uint32_t*)(gsrc + (size_t)img * HW + y * 128))[tid & 31];
    }
    __syncthreads();

    // ---- load kw fragments into registers ----------------------------------
    const bool compute = ((unsigned)y < 128u) && (y >= r0 - 4) && (y < r0 + 20);
    float kw[9][4];
    if (compute) {
        #pragma unroll
        for (int k = 0; k < 4; ++k) {
            float4 v = *(const float4*)&plane[k * 3328 + rel * 128 + xc];
            kw[k][0] = v.x; kw[k][1] = v.y; kw[k][2] = v.z; kw[k][3] = v.w;
        }
        kw[4][0] = kw[4][1] = kw[4][2] = kw[4][3] = 3.0f;  // center, exact
        #pragma unroll
        for (int k = 5; k < 9; ++k) {
            const int dy = k / 3 - 1, dx = k % 3 - 1;
            const int ry = y + dy, prow = ry - w0;
            #pragma unroll
            for (int j = 0; j < 4; ++j) {
                const int nx = xc + j + dx;
                kw[k][j] = ((unsigned)ry < 128u && (unsigned)nx < 128u)
                               ? plane[(8 - k) * 3328 + prow * 128 + nx]
                               : 0.0f;
            }
        }
    }

    // ---- 5 sweeps, branchless taps from registers --------------------------
    const float l45 = 0.7985076962177716f;  // -log(0.45f)
    const float l55 = 0.5978370007556204f;  // -log(0.55f)
    float* om = out + NM + (size_t)img * HW;
    int sA = 0, cnt = 0;
    for (int s = 0; s < 5; ++s) {
        const int lo = (r0 - 4 + s < 0) ? 0 : r0 - 4 + s;
        const int hi = (r0 + 20 - s > 128) ? 128 : r0 + 20 - s;
        const bool last = (s == 4);
        const bool act = compute && (y >= lo) && (y < hi);
        if (act) {
            // state bytes rows y-1..y+1, cols xc-1..xc+4
            unsigned char rb[3][6];
            const uint32_t* sw = &stw[sA][0];
            #pragma unroll
            for (int r = 0; r < 3; ++r) {
                const int ry = y + r - 1;
                if ((unsigned)ry < 128u) {
                    const int base = (ry - w0) * 32 + (xc >> 2);
                    const uint32_t wm = (xc > 0) ? sw[base - 1] : 0u;
                    const uint32_t wc = sw[base];
                    const uint32_t wp = (xc < 124) ? sw[base + 1] : 0u;
                    rb[r][0] = wm >> 24;
                    rb[r][1] = wc & 0xff; rb[r][2] = (wc >> 8) & 0xff;
                    rb[r][3] = (wc >> 16) & 0xff; rb[r][4] = wc >> 24;
                    rb[r][5] = wp & 0xff;
                } else {
                    #pragma unroll
                    for (int m = 0; m < 6; ++m) rb[r][m] = 0;  // kw==0 there
                }
            }
            float a0[4] = {0.f, 0.f, 0.f, 0.f}, a1[4] = {0.f, 0.f, 0.f, 0.f};
            #pragma unroll
            for (int k = 0; k < 9; ++k) {
                #pragma unroll
                for (int j = 0; j < 4; ++j) {
                    const float kwv = kw[k][j];
                    const unsigned char sq = rb[k / 3][j + (k % 3)];
                    const float lx1 = (sq & 1) ? l55 : l45;
                    const float lx0 = (sq & 2) ? l55 : l45;
                    const float t1 = lx1 * kwv;   // mul then add (numpy order)
                    const float t0 = lx0 * kwv;
                    a1[j] = a1[j] + t1;
                    a0[j] = a0[j] + t0;
                }
            }
            // epilogue (proven exact sequence)
            uint32_t ow = 0;
            float mv[4];
            int c1 = 0;
            #pragma unroll
            for (int j = 0; j < 4; ++j) {
                const unsigned char sc = rb[1][j + 1];
                const float tval = (sc & 4) ? 1.0f : 0.0f;
                const float e1 = expf(-a1[j]);
                const float e0 = expf(-a0[j]);
                const float m1 = e1 * tval;
                const float f1 = m1 + 1e-6f;
                const float f0 = e0 + 1e-6f;
                const float den = f0 + f1;
                const float r1 = f1 / den;
                const float r0v = f0 / den;
                const int s1 = (r1 > 0.5f) ? 1 : 0;
                const int s0 = (r0v > 0.5f) ? 1 : 0;
                mv[j] = (float)s1;
                c1 += s1;
                ow |= (uint32_t)(s1 | (s0 << 1) | (sc & 4)) << (8 * j);
            }
            if (!last) {
                stw[sA ^ 1][(y - w0) * 32 + (xc >> 2)] = ow;
            } else if (FIRST) {
                ((uint32_t*)(gdst2 + (size_t)img * HW))[y * 32 + (xc >> 2)] = ow;
            } else {
                *(float4*)(om + y * 128 + xc) = make_float4(mv[0], mv[1], mv[2], mv[3]);
                cnt = c1;
            }
        }
        __syncthreads();
        sA ^= 1;
    }

    // ---- phase B tail: counts + valid (proven ticket) ----------------------
    if (!FIRST) {
        int* cred = (int*)plane;
        cred[tid] = cnt;
        if (tid < 192) cred[832 + tid] = 0;
        __syncthreads();
        for (int off = 512; off > 0; off >>= 1) {
            if (tid < off) cred[tid] += cred[tid + off];
            __syncthreads();
        }
        int* flag = (int*)&stw[0][0];
        if (tid == 0) {
            atomicAdd(&counters[img], cred[0]);
            __threadfence();
            int old = atomicAdd(&counters[NI], 1);
            flag[0] = (old == 511) ? 1 : 0;
        }
        __syncthreads();
        if (flag[0] && tid < NI) {
            int c = atomicAdd(&counters[tid], 0);
            // 16384*0.05 = 819.2, 16384*0.95 = 15564.8; counts are integers
            out[NM + (size_t)NI * HW + tid] = (c >= 820 && c <= 15564) ? 1.0f : 0.0f;
        }
    }
}

extern "C" void kernel_launch(void* const* d_in, const int* in_sizes, int n_in,
                              void* d_out, int out_size, void* d_ws, size_t ws_size,
                              hipStream_t stream) {
    const float* seg = (const float*)d_in[0];
    const float* cate_scores = (const float*)d_in[1];
    const float* feat = (const float*)d_in[2];
    const float* x = (const float*)d_in[3];
    const float* targets = (const float*)d_in[4];
    const int* labels = (const int*)d_in[5];
    float* out = (float*)d_out;
    char* ws = (char*)d_ws;

    unsigned char* state = (unsigned char*)(ws + OFF_STATE);
    unsigned char* state2 = (unsigned char*)(ws + OFF_STATE2);
    unsigned long long* packed = (unsigned long long*)(ws + OFF_PACKED);
    float* diouT = (float*)(ws + OFF_DIOUT);
    float* compm = (float*)(ws + OFF_COMPM);
    int* counters = (int*)(ws + OFF_CNT);

    setup_kernel<<<512, 256, 0, stream>>>(seg, x, targets, state, packed, counters);
    diou_compm_kernel<<<NM, 256, 0, stream>>>(packed, labels, diouT, compm);
    crf5_kernel<true><<<512, 832, 0, stream>>>(feat, cate_scores, diouT, compm,
                                               state, state2, out, counters);
    crf5_kernel<false><<<512, 832, 0, stream>>>(feat, cate_scores, diouT, compm,
                                                state2, nullptr, out, counters);
}